// Round 3
// baseline (10823.379 us; speedup 1.0000x reference)
//
#include <hip/hip_runtime.h>
#include <stdint.h>

#define BSZ  128
#define TLEN 8192
#define MDIM 64
#define SDIM 512
#define NEG_BIG (-1e30f)

// ---- 8-bit dot product: 4 MACs per instruction, exact i32 accumulation ----
#if __has_builtin(__builtin_amdgcn_udot4)
  #define QA 255
  __device__ __forceinline__ int dot4(unsigned a, unsigned b, int c) {
    return (int)__builtin_amdgcn_udot4(a, b, (unsigned)c, false);
  }
#elif __has_builtin(__builtin_amdgcn_sdot4)
  #define QA 127   // keep bytes in [0,127] so signed == unsigned
  __device__ __forceinline__ int dot4(unsigned a, unsigned b, int c) {
    return __builtin_amdgcn_sdot4((int)a, (int)b, c, false);
  }
#else
  #define QA 255
  __device__ __forceinline__ int dot4(unsigned a, unsigned b, int c) {
    c += (int)((a & 0xffu) * (b & 0xffu));
    c += (int)(((a >> 8) & 0xffu) * ((b >> 8) & 0xffu));
    c += (int)(((a >> 16) & 0xffu) * ((b >> 16) & 0xffu));
    c += (int)((a >> 24) * (b >> 24));
    return c;
  }
#endif

// Wave-wide (64-lane) max via DPP, no LDS, ~6 serial VALU steps.
// old=v + bound_ctrl=false => invalid lanes keep v => fmax(v,v)=v (safe).
__device__ __forceinline__ float wave_max_f32(float x) {
  int v = __builtin_bit_cast(int, x);
#define DPP_STEP(ctrl)                                                        \
  {                                                                           \
    int o = __builtin_amdgcn_update_dpp(v, v, ctrl, 0xf, 0xf, false);         \
    v = __builtin_bit_cast(int, fmaxf(__builtin_bit_cast(float, v),           \
                                      __builtin_bit_cast(float, o)));         \
  }
  DPP_STEP(0x111)  // row_shr:1
  DPP_STEP(0x112)  // row_shr:2
  DPP_STEP(0x114)  // row_shr:4
  DPP_STEP(0x118)  // row_shr:8  -> lane15 of each row16 has row max
  DPP_STEP(0x142)  // row_bcast15 -> lane31 has max(0..31)
  DPP_STEP(0x143)  // row_bcast31 -> lane63 has max(0..63)
#undef DPP_STEP
  return __builtin_bit_cast(float, __builtin_amdgcn_readlane(v, 63));
}

// Extract symbol index from one-hot rows: sym[b,t] = argmax_m x[b,t,m]
__global__ void sym_kernel(const float* __restrict__ x, uint8_t* __restrict__ sym) {
  int i = blockIdx.x * blockDim.x + threadIdx.x;  // flat (b,t)
  const float4* p = (const float4*)(x + (size_t)i * MDIM);
  int idx = 0;
  #pragma unroll
  for (int j = 0; j < 16; ++j) {
    float4 v = p[j];
    if (v.x > 0.5f) idx = 4*j + 0;
    if (v.y > 0.5f) idx = 4*j + 1;
    if (v.z > 0.5f) idx = 4*j + 2;
    if (v.w > 0.5f) idx = 4*j + 3;
  }
  sym[i] = (uint8_t)idx;
}

// Per-column max of A (for quantization scale). One 64-thread block per column.
__global__ void colmax_kernel(const float* __restrict__ A, float* __restrict__ cmax) {
  int c = blockIdx.x, l = threadIdx.x;
  float m = 0.f;
  for (int r = l; r < SDIM; r += 64) m = fmaxf(m, A[(size_t)r * SDIM + c]);
  #pragma unroll
  for (int off = 32; off; off >>= 1) m = fmaxf(m, __shfl_xor(m, off));
  if (l == 0) cmax[c] = m;
}

// Pack A column-major as u8 row-quads: Aq[c*128 + j] bytes = round(QA*A[4j+b][c]/cmax[c])
__global__ void pack_kernel(const float* __restrict__ A, const float* __restrict__ cmax,
                            unsigned* __restrict__ Aq) {
  int id = blockIdx.x * 256 + threadIdx.x;   // 512*128 = 65536 ids
  int c = id >> 7, j = id & 127;
  float s = (float)QA / cmax[c];
  unsigned q = 0;
  #pragma unroll
  for (int bb = 0; bb < 4; ++bb) {
    float v = A[(size_t)(4 * j + bb) * SDIM + c];
    int qi = (int)(v * s + 0.5f);
    if (qi > QA) qi = QA;
    q |= (unsigned)qi << (8 * bb);
  }
  Aq[c * 128 + j] = q;
}

// One block per batch; 512 threads, thread c owns state/column c end-to-end.
// A column (512 u8) lives in 128 VGPRs. Per-wave p-quantization (DPP max,
// no cross-wave reduce), 8 per-source-wave int accumulators rescaled at
// combine. Double-buffered 512B p vector -> ONE barrier per step.
__global__ __launch_bounds__(512, 2) void hmm_fwd(
    const unsigned* __restrict__ Aq, const float* __restrict__ cmax,
    const float* __restrict__ Bm, const uint8_t* __restrict__ sym,
    float* __restrict__ out) {
  const int b  = blockIdx.x;
  const int c  = threadIdx.x;        // 0..511
  const int wv = c >> 6;             // wave id 0..7

  __shared__ uint8_t p8[2][SDIM];    // quantized p, double-buffered
  __shared__ float   red[2][8];      // per-wave maxes, double-buffered
  __shared__ float   red2[8];        // final loglik reduce

  // ---- load this thread's A column into 128 packed registers ----
  unsigned Areg[128];
  {
    const uint4* src = (const uint4*)(Aq + (size_t)c * 128);
    #pragma unroll
    for (int j4 = 0; j4 < 32; ++j4) {
      uint4 v = src[j4];
      Areg[4*j4+0] = v.x; Areg[4*j4+1] = v.y;
      Areg[4*j4+2] = v.z; Areg[4*j4+3] = v.w;
    }
  }

  const uint8_t* symb = sym + (size_t)b * TLEN;
  const float cscale = cmax[c] * (1.0f / ((float)QA * (float)QA));

  // ---- init: alpha0 = log(B[sym0,:]+eps) + [0,-inf,...] ----
  int s0 = symb[0];
  float alphaReg = __logf(Bm[s0 * SDIM + c] + 1e-16f) + (c == 0 ? 0.f : NEG_BIG);
  int   symNext  = symb[1];
  float logE_cur = __logf(Bm[symNext * SDIM + c] + 1e-16f);
  symNext = symb[2];

  for (int step = 1; step < TLEN; ++step) {
    const int par = step & 1;

    // ---- pre-barrier: per-wave max, quantize own p, publish ----
    float m_w = wave_max_f32(alphaReg);
    float p   = __expf(alphaReg - m_w);
    p8[par][c] = (uint8_t)(p * (float)QA + 0.5f);
    if ((c & 63) == 0) red[par][wv] = m_w;
    __syncthreads();

    // ---- post-barrier: prefetches first (latency hides under dots) ----
    float eNxt  = Bm[symNext * SDIM + c];                       // global, L2-hot
    int   symNN = symb[(step + 2 <= TLEN - 1) ? step + 2 : TLEN - 1];
    float4 ra = *(const float4*)&red[par][0];                   // wave maxes 0..3
    float4 rb = *(const float4*)&red[par][4];                   // wave maxes 4..7

    // ---- dot: full column, 8 per-source-wave accumulators ----
    const uint32_t* pw = (const uint32_t*)p8[par];
    int a0=0,a1=0,a2=0,a3=0,a4=0,a5=0,a6=0,a7=0;
    #pragma unroll
    for (int j = 0; j < 16; j += 4) {
      uint4 P0 = *(const uint4*)(pw + 0*16 + j);
      uint4 P1 = *(const uint4*)(pw + 1*16 + j);
      uint4 P2 = *(const uint4*)(pw + 2*16 + j);
      uint4 P3 = *(const uint4*)(pw + 3*16 + j);
      uint4 P4 = *(const uint4*)(pw + 4*16 + j);
      uint4 P5 = *(const uint4*)(pw + 5*16 + j);
      uint4 P6 = *(const uint4*)(pw + 6*16 + j);
      uint4 P7 = *(const uint4*)(pw + 7*16 + j);
      #pragma unroll
      for (int jj = 0; jj < 4; ++jj) {
        a0 = dot4(((const unsigned*)&P0)[jj], Areg[0*16 + j + jj], a0);
        a1 = dot4(((const unsigned*)&P1)[jj], Areg[1*16 + j + jj], a1);
        a2 = dot4(((const unsigned*)&P2)[jj], Areg[2*16 + j + jj], a2);
        a3 = dot4(((const unsigned*)&P3)[jj], Areg[3*16 + j + jj], a3);
        a4 = dot4(((const unsigned*)&P4)[jj], Areg[4*16 + j + jj], a4);
        a5 = dot4(((const unsigned*)&P5)[jj], Areg[5*16 + j + jj], a5);
        a6 = dot4(((const unsigned*)&P6)[jj], Areg[6*16 + j + jj], a6);
        a7 = dot4(((const unsigned*)&P7)[jj], Areg[7*16 + j + jj], a7);
      }
    }

    // ---- combine: rescale per-source-wave partials, log, emit ----
    float mref = fmaxf(fmaxf(fmaxf(ra.x, ra.y), fmaxf(ra.z, ra.w)),
                       fmaxf(fmaxf(rb.x, rb.y), fmaxf(rb.z, rb.w)));
    float r = 0.f;
    r = fmaf((float)a0, __expf(ra.x - mref), r);
    r = fmaf((float)a1, __expf(ra.y - mref), r);
    r = fmaf((float)a2, __expf(ra.z - mref), r);
    r = fmaf((float)a3, __expf(ra.w - mref), r);
    r = fmaf((float)a4, __expf(rb.x - mref), r);
    r = fmaf((float)a5, __expf(rb.y - mref), r);
    r = fmaf((float)a6, __expf(rb.z - mref), r);
    r = fmaf((float)a7, __expf(rb.w - mref), r);
    r *= cscale;
    alphaReg = __logf(r + 1e-16f) + mref + logE_cur;
    logE_cur = __logf(eNxt + 1e-16f);
    symNext  = symNN;
  }

  // ---- outputs: alpha_T then loglik ----
  out[(size_t)b * SDIM + c] = alphaReg;

  __syncthreads();                        // all reads of red[] in loop done
  float mx = wave_max_f32(alphaReg);
  if ((c & 63) == 0) red2[wv] = mx;
  __syncthreads();
  float mf = fmaxf(fmaxf(fmaxf(red2[0], red2[1]), fmaxf(red2[2], red2[3])),
                   fmaxf(fmaxf(red2[4], red2[5]), fmaxf(red2[6], red2[7])));

  float se = __expf(alphaReg - mf);
  #pragma unroll
  for (int off = 32; off; off >>= 1) se += __shfl_xor(se, off);
  __syncthreads();
  if ((c & 63) == 0) red2[wv] = se;
  __syncthreads();
  if (c == 0) {
    float tot = 0.f;
    #pragma unroll
    for (int k = 0; k < 8; ++k) tot += red2[k];
    out[(size_t)BSZ * SDIM + b] = __logf(tot + SDIM * 1e-16f) + mf;
  }
}

extern "C" void kernel_launch(void* const* d_in, const int* in_sizes, int n_in,
                              void* d_out, int out_size, void* d_ws, size_t ws_size,
                              hipStream_t stream) {
  const float* x  = (const float*)d_in[0];
  const float* A  = (const float*)d_in[1];
  const float* Bm = (const float*)d_in[2];
  float* out = (float*)d_out;

  uint8_t*  sym  = (uint8_t*)d_ws;                                  // 1 MB
  unsigned* Aq   = (unsigned*)((char*)d_ws + (1 << 20));            // 256 KB
  float*    cmax = (float*)((char*)d_ws + (1 << 20) + (256 << 10)); // 2 KB

  sym_kernel<<<(BSZ * TLEN) / 256, 256, 0, stream>>>(x, sym);
  colmax_kernel<<<SDIM, 64, 0, stream>>>(A, cmax);
  pack_kernel<<<(SDIM * 128) / 256, 256, 0, stream>>>(A, cmax, Aq);
  hmm_fwd<<<BSZ, 512, 0, stream>>>(Aq, cmax, Bm, sym, out);
}